// Round 4
// baseline (180.782 us; speedup 1.0000x reference)
//
#include <hip/hip_runtime.h>

// Problem constants (B,S,D)=(2,2048,1024), H=16, DH=64, WINDOW=128
#define SQ      2048
#define NB      2
#define NH      16
#define DHD     64
#define WIN     128
#define DMODEL  1024
#define TRIPLE  3072

typedef __attribute__((ext_vector_type(8))) short  short8;
typedef __attribute__((ext_vector_type(4))) float  f32x4;

__device__ __forceinline__ unsigned short f2bf(float f) {
  unsigned u = __float_as_uint(f);
  u += 0x7fff + ((u >> 16) & 1);   // RNE
  return (unsigned short)(u >> 16);
}

// direct global->LDS DMA, 16 B per lane; LDS dest = wave-uniform base + lane*16
__device__ __forceinline__ void load_lds16(const void* g, void* l) {
  __builtin_amdgcn_global_load_lds(
      (const __attribute__((address_space(1))) unsigned int*)g,
      (__attribute__((address_space(3))) unsigned int*)l, 16, 0, 0);
}

// ---------------------------------------------------------------- cast fp32 -> bf16
__global__ void cast_bf16_kernel(const float* __restrict__ in,
                                 unsigned short* __restrict__ out, int n4) {
  int idx = blockIdx.x * blockDim.x + threadIdx.x;
  if (idx >= n4) return;
  f32x4 v = ((const f32x4*)in)[idx];
  ushort4 o;
  o.x = f2bf(v[0]); o.y = f2bf(v[1]); o.z = f2bf(v[2]); o.w = f2bf(v[3]);
  ((ushort4*)out)[idx] = o;
}

// ------------------------------------------------- transpose + cast: in[K][N] fp32 -> out[N][K] bf16
__global__ void transpose_cast_kernel(const float* __restrict__ in,
                                      unsigned short* __restrict__ out,
                                      int K, int N) {
  __shared__ float tile[32][33];
  int n0 = blockIdx.x * 32, k0 = blockIdx.y * 32;
  int tx = threadIdx.x, ty = threadIdx.y;       // 32 x 8
#pragma unroll
  for (int r = 0; r < 4; ++r)
    tile[ty + 8 * r][tx] = in[(size_t)(k0 + ty + 8 * r) * N + (n0 + tx)];
  __syncthreads();
#pragma unroll
  for (int r = 0; r < 4; ++r)
    out[(size_t)(n0 + ty + 8 * r) * K + (k0 + tx)] = f2bf(tile[tx][ty + 8 * r]);
}

// ------------------------------------------------- C[M][N] = A[M][K]bf16 * Bt[N][K]bf16^T
// m97 structure: 128x128 tile, BK=64, 256 thr / 4 waves (64x64 subtile = 4x4 MFMA 16x16x32),
// global_load_lds width-16 staging into UNPADDED [128][64]-short LDS tiles.
template <bool BF16OUT>
__global__ __launch_bounds__(256) void gemm_bt_kernel(
    const unsigned short* __restrict__ A,
    const unsigned short* __restrict__ Bt,
    void* __restrict__ Cv,
    int M, int N, int K) {
  __shared__ short lsA[128 * 64];
  __shared__ short lsB[128 * 64];
  int tid  = threadIdx.x;
  int wave = tid >> 6, lane = tid & 63;
  int quad = lane >> 4, l16 = lane & 15;
  int wm = (wave >> 1) * 64, wn = (wave & 1) * 64;
  int m0 = blockIdx.x * 128, n0 = blockIdx.y * 128;

  f32x4 acc[4][4] = {};

  const short* Ag = (const short*)A;
  const short* Bg = (const short*)Bt;

  // staging geometry: wave w covers tile rows [32w, 32w+32); one inst = 8 rows
  int srow = (lane >> 3);          // 0..7 within an instruction's 8-row span
  int scol = (lane & 7) * 8;       // 0..56

  for (int k0 = 0; k0 < K; k0 += 64) {
    const short* Ab = Ag + (size_t)(m0 + wave * 32) * K + k0;
    const short* Bb = Bg + (size_t)(n0 + wave * 32) * K + k0;
#pragma unroll
    for (int inst = 0; inst < 4; ++inst) {
      int r = inst * 8 + srow;
      load_lds16(Ab + (size_t)r * K + scol, &lsA[(wave * 32 + inst * 8) * 64]);
      load_lds16(Bb + (size_t)r * K + scol, &lsB[(wave * 32 + inst * 8) * 64]);
    }
    __syncthreads();
#pragma unroll
    for (int ks = 0; ks < 2; ++ks) {
      short8 af[4], bf[4];
#pragma unroll
      for (int t = 0; t < 4; ++t) {
        af[t] = *(const short8*)(&lsA[(wm + t * 16 + l16) * 64 + ks * 32 + quad * 8]);
        bf[t] = *(const short8*)(&lsB[(wn + t * 16 + l16) * 64 + ks * 32 + quad * 8]);
      }
#pragma unroll
      for (int mt = 0; mt < 4; ++mt)
#pragma unroll
        for (int nt = 0; nt < 4; ++nt)
          acc[mt][nt] = __builtin_amdgcn_mfma_f32_16x16x32_bf16(
              af[mt], bf[nt], acc[mt][nt], 0, 0, 0);
    }
    __syncthreads();
  }
  // C/D layout: col = lane&15, row = quad*4 + reg
#pragma unroll
  for (int mt = 0; mt < 4; ++mt)
#pragma unroll
    for (int nt = 0; nt < 4; ++nt)
#pragma unroll
      for (int r = 0; r < 4; ++r) {
        int row = m0 + wm + mt * 16 + quad * 4 + r;
        int col = n0 + wn + nt * 16 + l16;
        if (BF16OUT)
          ((unsigned short*)Cv)[(size_t)row * N + col] = f2bf(acc[mt][nt][r]);
        else
          ((float*)Cv)[(size_t)row * N + col] = acc[mt][nt][r];
      }
}

// ------------------------------------------------- MFMA flash attention (bf16 in/out)
// qkvb bf16 [NB*SQ][3072] (q +0, k +1024, v +2048; per head h*64+d)
// block = 256 thr / 4 waves per (64-query group, head, b); wave w owns 16 queries.
// 6 chunks of 32 keys, cooperative double-buffered LDS staging (K row-major, V transposed).
#define KSTR 72   // K tile row stride (shorts)
#define VSTR 40   // V^T tile row stride (shorts)
#define PSTR 36   // P tile row stride (shorts)
__global__ __launch_bounds__(256) void attn_kernel(
    const unsigned short* __restrict__ qkvb,
    unsigned short* __restrict__ attnout) {
  __shared__ short Kl[2][32 * KSTR];
  __shared__ short Vt[2][64 * VSTR];
  __shared__ short Pl[4][16 * PSTR];

  int i0 = blockIdx.x * 64, h = blockIdx.y, b = blockIdx.z;
  int tid = threadIdx.x, wave = tid >> 6, lane = tid & 63;
  int quad = lane >> 4, l16 = lane & 15;
  const unsigned short* base = qkvb + (size_t)b * SQ * TRIPLE;

  // Q A-frags (A[m=lane&15][k=quad*8+e]), held across the whole loop
  short8 qa[2];
  {
    int qi = i0 + wave * 16 + l16;
    const unsigned short* qrow = base + (size_t)qi * TRIPLE + h * DHD;
    qa[0] = *(const short8*)(qrow + quad * 8);
    qa[1] = *(const short8*)(qrow + 32 + quad * 8);
  }

  f32x4 o[4] = {};
  float mrow[4] = {-1e30f, -1e30f, -1e30f, -1e30f};
  float lrow[4] = {0.f, 0.f, 0.f, 0.f};

  int cstart = (i0 >= WIN) ? 0 : ((WIN - i0) >> 5);
  int nch = 6 - cstart;
  int jc0 = i0 - WIN + cstart * 32;   // >= 0 by construction

  int srow_ = tid >> 3;               // 0..31 (staging row)
  int scol_ = (tid & 7) * 8;          // 0..56 (staging col)

  // ---- stage chunk c into buffer bb (all 256 threads) ----
  auto stage = [&](int c, int bb) {
    int j = jc0 + c * 32 + srow_;
    const unsigned short* kr = base + (size_t)j * TRIPLE + DMODEL + h * DHD + scol_;
    *(short8*)(&Kl[bb][srow_ * KSTR + scol_]) = *(const short8*)kr;
    const unsigned short* vr = base + (size_t)j * TRIPLE + 2 * DMODEL + h * DHD + scol_;
    short8 vv = *(const short8*)vr;
#pragma unroll
    for (int e = 0; e < 8; ++e)
      Vt[bb][(scol_ + e) * VSTR + srow_] = vv[e];
  };

  stage(0, 0);
  __syncthreads();

  int irow = i0 + wave * 16 + quad * 4;   // + r = query index of acc row r

  for (int c = 0; c < nch; ++c) {
    int bb = c & 1;
    if (c + 1 < nch) stage(c + 1, bb ^ 1);
    int jc = jc0 + c * 32;

    // ---- S = Q * K^T (C-layout: row=quad*4+r, col=lane&15) ----
    f32x4 s[2] = {};
#pragma unroll
    for (int ks = 0; ks < 2; ++ks) {
#pragma unroll
      for (int nt = 0; nt < 2; ++nt) {
        short8 bk = *(const short8*)(&Kl[bb][(nt * 16 + l16) * KSTR + ks * 32 + quad * 8]);
        s[nt] = __builtin_amdgcn_mfma_f32_16x16x32_bf16(qa[ks], bk, s[nt], 0, 0, 0);
      }
    }
    // ---- scale + window mask ----
#pragma unroll
    for (int nt = 0; nt < 2; ++nt)
#pragma unroll
      for (int r = 0; r < 4; ++r) {
        int i_ = irow + r;
        int j_ = jc + nt * 16 + l16;
        bool ok = (j_ <= i_) && (j_ > i_ - WIN);
        s[nt][r] = ok ? s[nt][r] * 0.125f : -1e30f;
      }
    // ---- online softmax (row-wise over 32 cols: 2 tiles x 16 lanes) ----
    float rm[4];
#pragma unroll
    for (int r = 0; r < 4; ++r) rm[r] = fmaxf(s[0][r], s[1][r]);
#pragma unroll
    for (int off = 1; off < 16; off <<= 1)
#pragma unroll
      for (int r = 0; r < 4; ++r) rm[r] = fmaxf(rm[r], __shfl_xor(rm[r], off, 64));
    float al[4];
#pragma unroll
    for (int r = 0; r < 4; ++r) {
      float mn = fmaxf(mrow[r], rm[r]);
      al[r] = __expf(mrow[r] - mn);
      mrow[r] = mn;
    }
    f32x4 p[2];
#pragma unroll
    for (int nt = 0; nt < 2; ++nt)
#pragma unroll
      for (int r = 0; r < 4; ++r) p[nt][r] = __expf(s[nt][r] - mrow[r]);
    float rs[4];
#pragma unroll
    for (int r = 0; r < 4; ++r) rs[r] = p[0][r] + p[1][r];
#pragma unroll
    for (int off = 1; off < 16; off <<= 1)
#pragma unroll
      for (int r = 0; r < 4; ++r) rs[r] += __shfl_xor(rs[r], off, 64);
#pragma unroll
    for (int r = 0; r < 4; ++r) lrow[r] = lrow[r] * al[r] + rs[r];
#pragma unroll
    for (int nt = 0; nt < 4; ++nt)
#pragma unroll
      for (int r = 0; r < 4; ++r) o[nt][r] *= al[r];
    // ---- P: C-layout -> LDS -> A-frag (per-wave private; DS in-order per wave) ----
#pragma unroll
    for (int nt = 0; nt < 2; ++nt)
#pragma unroll
      for (int r = 0; r < 4; ++r)
        Pl[wave][(quad * 4 + r) * PSTR + nt * 16 + l16] = f2bf(p[nt][r]);
    short8 pa = *(const short8*)(&Pl[wave][l16 * PSTR + quad * 8]);
    // ---- O += P * V  (V^T staged: B-frag = Vt[d=nt*16+l16][j=quad*8+e]) ----
#pragma unroll
    for (int nt = 0; nt < 4; ++nt) {
      short8 bv = *(const short8*)(&Vt[bb][(nt * 16 + l16) * VSTR + quad * 8]);
      o[nt] = __builtin_amdgcn_mfma_f32_16x16x32_bf16(pa, bv, o[nt], 0, 0, 0);
    }
    __syncthreads();
  }

  // ---- epilogue ----
  float inv[4];
#pragma unroll
  for (int r = 0; r < 4; ++r) inv[r] = 1.0f / lrow[r];
#pragma unroll
  for (int nt = 0; nt < 4; ++nt)
#pragma unroll
    for (int r = 0; r < 4; ++r) {
      int i_ = irow + r;
      int d_ = nt * 16 + l16;
      attnout[(size_t)(b * SQ + i_) * DMODEL + h * DHD + d_] = f2bf(o[nt][r] * inv[r]);
    }
}

// ----------------------------------------------------------------------------------
extern "C" void kernel_launch(void* const* d_in, const int* in_sizes, int n_in,
                              void* d_out, int out_size, void* d_ws, size_t ws_size,
                              hipStream_t stream) {
  const float* x     = (const float*)d_in[0];   // [2,2048,1024]
  const float* w_qkv = (const float*)d_in[1];   // [1024,3072]
  const float* w_out = (const float*)d_in[2];   // [1024,1024]
  float* out = (float*)d_out;                   // [2,2048,1024] fp32

  char* ws = (char*)d_ws;
  // workspace layout (48 MB total)
  unsigned short* xb    = (unsigned short*)(ws);               //  8 MB  [4096][1024] bf16
  unsigned short* wqkvT = (unsigned short*)(ws + 8388608);     //  6 MB  [3072][1024] bf16
  unsigned short* woutT = (unsigned short*)(ws + 14680064);    //  2 MB  [1024][1024] bf16
  unsigned short* qkvb  = (unsigned short*)(ws + 16777216);    // 24 MB  [4096][3072] bf16
  unsigned short* attn  = (unsigned short*)(ws + 41943040);    //  8 MB  [4096][1024] bf16

  // 1. cast x to bf16
  cast_bf16_kernel<<<4096, 256, 0, stream>>>(x, xb, (NB * SQ * DMODEL) / 4);
  // 2. transpose+cast weights: [K][N] -> [N][K]
  dim3 tb(32, 8);
  transpose_cast_kernel<<<dim3(TRIPLE / 32, DMODEL / 32), tb, 0, stream>>>(w_qkv, wqkvT, DMODEL, TRIPLE);
  transpose_cast_kernel<<<dim3(DMODEL / 32, DMODEL / 32), tb, 0, stream>>>(w_out, woutT, DMODEL, DMODEL);
  // 3. qkvb = xb @ wqkvT^T   (bf16 out)
  gemm_bt_kernel<true><<<dim3((NB * SQ) / 128, TRIPLE / 128), 256, 0, stream>>>(
      xb, wqkvT, qkvb, NB * SQ, TRIPLE, DMODEL);
  // 4. MFMA flash attention
  attn_kernel<<<dim3(SQ / 64, NH, NB), 256, 0, stream>>>(qkvb, attn);
  // 5. out = attn @ woutT^T  (fp32 out)
  gemm_bt_kernel<false><<<dim3((NB * SQ) / 128, DMODEL / 128), 256, 0, stream>>>(
      attn, woutT, out, NB * SQ, DMODEL, DMODEL);
}

// Round 5
// 160.164 us; speedup vs baseline: 1.1287x; 1.1287x over previous
//
#include <hip/hip_runtime.h>

// Problem constants (B,S,D)=(2,2048,1024), H=16, DH=64, WINDOW=128
#define SQ      2048
#define NB      2
#define NH      16
#define DHD     64
#define WIN     128
#define DMODEL  1024
#define TRIPLE  3072

typedef __attribute__((ext_vector_type(8))) short  short8;
typedef __attribute__((ext_vector_type(4))) float  f32x4;

__device__ __forceinline__ unsigned short f2bf(float f) {
  unsigned u = __float_as_uint(f);
  u += 0x7fff + ((u >> 16) & 1);   // RNE
  return (unsigned short)(u >> 16);
}

// direct global->LDS DMA, 16 B per lane; LDS dest = wave-uniform base + lane*16
__device__ __forceinline__ void load_lds16(const void* g, void* l) {
  __builtin_amdgcn_global_load_lds(
      (const __attribute__((address_space(1))) unsigned int*)g,
      (__attribute__((address_space(3))) unsigned int*)l, 16, 0, 0);
}

// ---------------------------------------------------------------- cast fp32 -> bf16
__global__ void cast_bf16_kernel(const float* __restrict__ in,
                                 unsigned short* __restrict__ out, int n4) {
  int idx = blockIdx.x * blockDim.x + threadIdx.x;
  if (idx >= n4) return;
  f32x4 v = ((const f32x4*)in)[idx];
  ushort4 o;
  o.x = f2bf(v[0]); o.y = f2bf(v[1]); o.z = f2bf(v[2]); o.w = f2bf(v[3]);
  ((ushort4*)out)[idx] = o;
}

// ------------------------------------------------- transpose + cast: in[K][N] fp32 -> out[N][K] bf16
__global__ void transpose_cast_kernel(const float* __restrict__ in,
                                      unsigned short* __restrict__ out,
                                      int K, int N) {
  __shared__ float tile[32][33];
  int n0 = blockIdx.x * 32, k0 = blockIdx.y * 32;
  int tx = threadIdx.x, ty = threadIdx.y;       // 32 x 8
#pragma unroll
  for (int r = 0; r < 4; ++r)
    tile[ty + 8 * r][tx] = in[(size_t)(k0 + ty + 8 * r) * N + (n0 + tx)];
  __syncthreads();
#pragma unroll
  for (int r = 0; r < 4; ++r)
    out[(size_t)(n0 + ty + 8 * r) * K + (k0 + tx)] = f2bf(tile[tx][ty + 8 * r]);
}

// ------------------------------------------------- C[M][N] = A[M][K]bf16 * Bt[N][K]bf16^T
// m97 structure + XOR chunk swizzle: 128x128 tile, BK=64, 256 thr / 4 waves,
// global_load_lds width-16 staging into [128][64]-short LDS tiles where
// LDS slot (row, c) holds global chunk (row, c ^ (row&7))  [16B chunks, 8/row].
// Frag reads hit slot (c ^ (l16&7)) -> 2-way bank aliasing (free, m136).
template <bool BF16OUT>
__global__ __launch_bounds__(256) void gemm_bt_kernel(
    const unsigned short* __restrict__ A,
    const unsigned short* __restrict__ Bt,
    void* __restrict__ Cv,
    int M, int N, int K) {
  __shared__ short lsA[128 * 64];
  __shared__ short lsB[128 * 64];
  int tid  = threadIdx.x;
  int wave = tid >> 6, lane = tid & 63;
  int quad = lane >> 4, l16 = lane & 15;
  int wm = (wave >> 1) * 64, wn = (wave & 1) * 64;
  int m0 = blockIdx.x * 128, n0 = blockIdx.y * 128;

  f32x4 acc[4][4] = {};

  const short* Ag = (const short*)A;
  const short* Bg = (const short*)Bt;

  // staging geometry: wave w covers tile rows [32w, 32w+32); one inst = 8 rows.
  // lane -> (row8 = lane>>3, slot = lane&7); fetch global chunk slot^row8.
  int row8 = lane >> 3;                       // 0..7
  int gcol = ((lane & 7) ^ row8) * 8;         // swizzled source column (shorts)

  // frag-read swizzle: slot for chunk c at row with (row&7)==l16&7
  int sw = (l16 & 7) * 8;                     // XOR'ed into chunk*8 (shorts)

  for (int k0 = 0; k0 < K; k0 += 64) {
    const short* Ab = Ag + (size_t)(m0 + wave * 32) * K + k0;
    const short* Bb = Bg + (size_t)(n0 + wave * 32) * K + k0;
#pragma unroll
    for (int inst = 0; inst < 4; ++inst) {
      int r = inst * 8 + row8;
      load_lds16(Ab + (size_t)r * K + gcol, &lsA[(wave * 32 + inst * 8) * 64]);
      load_lds16(Bb + (size_t)r * K + gcol, &lsB[(wave * 32 + inst * 8) * 64]);
    }
    __syncthreads();
#pragma unroll
    for (int ks = 0; ks < 2; ++ks) {
      short8 af[4], bf[4];
#pragma unroll
      for (int t = 0; t < 4; ++t) {
        int coff = ((ks * 32 + quad * 8) ^ sw);   // (chunk*8) ^ ((l16&7)*8)
        af[t] = *(const short8*)(&lsA[(wm + t * 16 + l16) * 64 + coff]);
        bf[t] = *(const short8*)(&lsB[(wn + t * 16 + l16) * 64 + coff]);
      }
#pragma unroll
      for (int mt = 0; mt < 4; ++mt)
#pragma unroll
        for (int nt = 0; nt < 4; ++nt)
          acc[mt][nt] = __builtin_amdgcn_mfma_f32_16x16x32_bf16(
              af[mt], bf[nt], acc[mt][nt], 0, 0, 0);
    }
    __syncthreads();
  }
  // C/D layout: col = lane&15, row = quad*4 + reg
#pragma unroll
  for (int mt = 0; mt < 4; ++mt)
#pragma unroll
    for (int nt = 0; nt < 4; ++nt)
#pragma unroll
      for (int r = 0; r < 4; ++r) {
        int row = m0 + wm + mt * 16 + quad * 4 + r;
        int col = n0 + wn + nt * 16 + l16;
        if (BF16OUT)
          ((unsigned short*)Cv)[(size_t)row * N + col] = f2bf(acc[mt][nt][r]);
        else
          ((float*)Cv)[(size_t)row * N + col] = acc[mt][nt][r];
      }
}

// ------------------------------------------------- MFMA flash attention (bf16 in/out)
// qkvb bf16 [NB*SQ][3072] (q +0, k +1024, v +2048; per head h*64+d)
// block = 256 thr / 4 waves per (64-query group, head, b); wave w owns 16 queries.
// 6 chunks of 32 keys, cooperative double-buffered LDS staging (K row-major, V transposed).
#define KSTR 72   // K tile row stride (shorts)
#define VSTR 40   // V^T tile row stride (shorts)
#define PSTR 36   // P tile row stride (shorts)
__global__ __launch_bounds__(256) void attn_kernel(
    const unsigned short* __restrict__ qkvb,
    unsigned short* __restrict__ attnout) {
  __shared__ short Kl[2][32 * KSTR];
  __shared__ short Vt[2][64 * VSTR];
  __shared__ short Pl[4][16 * PSTR];

  int i0 = blockIdx.x * 64, h = blockIdx.y, b = blockIdx.z;
  int tid = threadIdx.x, wave = tid >> 6, lane = tid & 63;
  int quad = lane >> 4, l16 = lane & 15;
  const unsigned short* base = qkvb + (size_t)b * SQ * TRIPLE;

  // Q A-frags (A[m=lane&15][k=quad*8+e]), held across the whole loop
  short8 qa[2];
  {
    int qi = i0 + wave * 16 + l16;
    const unsigned short* qrow = base + (size_t)qi * TRIPLE + h * DHD;
    qa[0] = *(const short8*)(qrow + quad * 8);
    qa[1] = *(const short8*)(qrow + 32 + quad * 8);
  }

  f32x4 o[4] = {};
  float mrow[4] = {-1e30f, -1e30f, -1e30f, -1e30f};
  float lrow[4] = {0.f, 0.f, 0.f, 0.f};

  int cstart = (i0 >= WIN) ? 0 : ((WIN - i0) >> 5);
  int nch = 6 - cstart;
  int jc0 = i0 - WIN + cstart * 32;   // >= 0 by construction

  int srow_ = tid >> 3;               // 0..31 (staging row)
  int scol_ = (tid & 7) * 8;          // 0..56 (staging col)

  // ---- stage chunk c into buffer bb (all 256 threads) ----
  auto stage = [&](int c, int bb) {
    int j = jc0 + c * 32 + srow_;
    const unsigned short* kr = base + (size_t)j * TRIPLE + DMODEL + h * DHD + scol_;
    *(short8*)(&Kl[bb][srow_ * KSTR + scol_]) = *(const short8*)kr;
    const unsigned short* vr = base + (size_t)j * TRIPLE + 2 * DMODEL + h * DHD + scol_;
    short8 vv = *(const short8*)vr;
#pragma unroll
    for (int e = 0; e < 8; ++e)
      Vt[bb][(scol_ + e) * VSTR + srow_] = vv[e];
  };

  stage(0, 0);
  __syncthreads();

  int irow = i0 + wave * 16 + quad * 4;   // + r = query index of acc row r

  for (int c = 0; c < nch; ++c) {
    int bb = c & 1;
    if (c + 1 < nch) stage(c + 1, bb ^ 1);
    int jc = jc0 + c * 32;

    // ---- S = Q * K^T (C-layout: row=quad*4+r, col=lane&15) ----
    f32x4 s[2] = {};
#pragma unroll
    for (int ks = 0; ks < 2; ++ks) {
#pragma unroll
      for (int nt = 0; nt < 2; ++nt) {
        short8 bk = *(const short8*)(&Kl[bb][(nt * 16 + l16) * KSTR + ks * 32 + quad * 8]);
        s[nt] = __builtin_amdgcn_mfma_f32_16x16x32_bf16(qa[ks], bk, s[nt], 0, 0, 0);
      }
    }
    // ---- scale + window mask ----
#pragma unroll
    for (int nt = 0; nt < 2; ++nt)
#pragma unroll
      for (int r = 0; r < 4; ++r) {
        int i_ = irow + r;
        int j_ = jc + nt * 16 + l16;
        bool ok = (j_ <= i_) && (j_ > i_ - WIN);
        s[nt][r] = ok ? s[nt][r] * 0.125f : -1e30f;
      }
    // ---- online softmax (row-wise over 32 cols: 2 tiles x 16 lanes) ----
    float rm[4];
#pragma unroll
    for (int r = 0; r < 4; ++r) rm[r] = fmaxf(s[0][r], s[1][r]);
#pragma unroll
    for (int off = 1; off < 16; off <<= 1)
#pragma unroll
      for (int r = 0; r < 4; ++r) rm[r] = fmaxf(rm[r], __shfl_xor(rm[r], off, 64));
    float al[4];
#pragma unroll
    for (int r = 0; r < 4; ++r) {
      float mn = fmaxf(mrow[r], rm[r]);
      al[r] = __expf(mrow[r] - mn);
      mrow[r] = mn;
    }
    f32x4 p[2];
#pragma unroll
    for (int nt = 0; nt < 2; ++nt)
#pragma unroll
      for (int r = 0; r < 4; ++r) p[nt][r] = __expf(s[nt][r] - mrow[r]);
    float rs[4];
#pragma unroll
    for (int r = 0; r < 4; ++r) rs[r] = p[0][r] + p[1][r];
#pragma unroll
    for (int off = 1; off < 16; off <<= 1)
#pragma unroll
      for (int r = 0; r < 4; ++r) rs[r] += __shfl_xor(rs[r], off, 64);
#pragma unroll
    for (int r = 0; r < 4; ++r) lrow[r] = lrow[r] * al[r] + rs[r];
#pragma unroll
    for (int nt = 0; nt < 4; ++nt)
#pragma unroll
      for (int r = 0; r < 4; ++r) o[nt][r] *= al[r];
    // ---- P: C-layout -> LDS -> A-frag (per-wave private; DS in-order per wave) ----
#pragma unroll
    for (int nt = 0; nt < 2; ++nt)
#pragma unroll
      for (int r = 0; r < 4; ++r)
        Pl[wave][(quad * 4 + r) * PSTR + nt * 16 + l16] = f2bf(p[nt][r]);
    short8 pa = *(const short8*)(&Pl[wave][l16 * PSTR + quad * 8]);
    // ---- O += P * V  (V^T staged: B-frag = Vt[d=nt*16+l16][j=quad*8+e]) ----
#pragma unroll
    for (int nt = 0; nt < 4; ++nt) {
      short8 bv = *(const short8*)(&Vt[bb][(nt * 16 + l16) * VSTR + quad * 8]);
      o[nt] = __builtin_amdgcn_mfma_f32_16x16x32_bf16(pa, bv, o[nt], 0, 0, 0);
    }
    __syncthreads();
  }

  // ---- epilogue ----
  float inv[4];
#pragma unroll
  for (int r = 0; r < 4; ++r) inv[r] = 1.0f / lrow[r];
#pragma unroll
  for (int nt = 0; nt < 4; ++nt)
#pragma unroll
    for (int r = 0; r < 4; ++r) {
      int i_ = irow + r;
      int d_ = nt * 16 + l16;
      attnout[(size_t)(b * SQ + i_) * DMODEL + h * DHD + d_] = f2bf(o[nt][r] * inv[r]);
    }
}

// ----------------------------------------------------------------------------------
extern "C" void kernel_launch(void* const* d_in, const int* in_sizes, int n_in,
                              void* d_out, int out_size, void* d_ws, size_t ws_size,
                              hipStream_t stream) {
  const float* x     = (const float*)d_in[0];   // [2,2048,1024]
  const float* w_qkv = (const float*)d_in[1];   // [1024,3072]
  const float* w_out = (const float*)d_in[2];   // [1024,1024]
  float* out = (float*)d_out;                   // [2,2048,1024] fp32

  char* ws = (char*)d_ws;
  // workspace layout (48 MB total)
  unsigned short* xb    = (unsigned short*)(ws);               //  8 MB  [4096][1024] bf16
  unsigned short* wqkvT = (unsigned short*)(ws + 8388608);     //  6 MB  [3072][1024] bf16
  unsigned short* woutT = (unsigned short*)(ws + 14680064);    //  2 MB  [1024][1024] bf16
  unsigned short* qkvb  = (unsigned short*)(ws + 16777216);    // 24 MB  [4096][3072] bf16
  unsigned short* attn  = (unsigned short*)(ws + 41943040);    //  8 MB  [4096][1024] bf16

  // 1. cast x to bf16
  cast_bf16_kernel<<<4096, 256, 0, stream>>>(x, xb, (NB * SQ * DMODEL) / 4);
  // 2. transpose+cast weights: [K][N] -> [N][K]
  dim3 tb(32, 8);
  transpose_cast_kernel<<<dim3(TRIPLE / 32, DMODEL / 32), tb, 0, stream>>>(w_qkv, wqkvT, DMODEL, TRIPLE);
  transpose_cast_kernel<<<dim3(DMODEL / 32, DMODEL / 32), tb, 0, stream>>>(w_out, woutT, DMODEL, DMODEL);
  // 3. qkvb = xb @ wqkvT^T   (bf16 out)
  gemm_bt_kernel<true><<<dim3((NB * SQ) / 128, TRIPLE / 128), 256, 0, stream>>>(
      xb, wqkvT, qkvb, NB * SQ, TRIPLE, DMODEL);
  // 4. MFMA flash attention
  attn_kernel<<<dim3(SQ / 64, NH, NB), 256, 0, stream>>>(qkvb, attn);
  // 5. out = attn @ woutT^T  (fp32 out)
  gemm_bt_kernel<false><<<dim3((NB * SQ) / 128, DMODEL / 128), 256, 0, stream>>>(
      attn, woutT, out, NB * SQ, DMODEL, DMODEL);
}

// Round 6
// 153.595 us; speedup vs baseline: 1.1770x; 1.0428x over previous
//
#include <hip/hip_runtime.h>

// Problem constants (B,S,D)=(2,2048,1024), H=16, DH=64, WINDOW=128
#define SQ      2048
#define NB      2
#define NH      16
#define DHD     64
#define WIN     128
#define DMODEL  1024
#define TRIPLE  3072

typedef __attribute__((ext_vector_type(8))) short  short8;
typedef __attribute__((ext_vector_type(4))) float  f32x4;

__device__ __forceinline__ unsigned short f2bf(float f) {
  unsigned u = __float_as_uint(f);
  u += 0x7fff + ((u >> 16) & 1);   // RNE
  return (unsigned short)(u >> 16);
}

// direct global->LDS DMA, 16 B per lane; LDS dest = wave-uniform base + lane*16
__device__ __forceinline__ void load_lds16(const void* g, void* l) {
  __builtin_amdgcn_global_load_lds(
      (const __attribute__((address_space(1))) unsigned int*)g,
      (__attribute__((address_space(3))) unsigned int*)l, 16, 0, 0);
}

// ------------------------------------------------- fused preprocessing (1 dispatch):
// blocks [0,4096)            : cast x fp32 -> bf16 (1024 elems/block)
// blocks [4096,7168)         : transpose+cast w_qkv [1024][3072] -> [3072][1024]
// blocks [7168,8192)         : transpose+cast w_out [1024][1024] -> [1024][1024]
__global__ __launch_bounds__(256) void prep_kernel(
    const float* __restrict__ x, const float* __restrict__ w_qkv,
    const float* __restrict__ w_out,
    unsigned short* __restrict__ xb, unsigned short* __restrict__ wqkvT,
    unsigned short* __restrict__ woutT) {
  __shared__ float tile[32][33];
  int blk = blockIdx.x, tid = threadIdx.x;
  if (blk < 4096) {
    int idx = blk * 256 + tid;
    f32x4 v = ((const f32x4*)x)[idx];
    ushort4 o;
    o.x = f2bf(v[0]); o.y = f2bf(v[1]); o.z = f2bf(v[2]); o.w = f2bf(v[3]);
    ((ushort4*)xb)[idx] = o;
    return;
  }
  const float* in;
  unsigned short* out;
  int K = DMODEL, N, t;
  if (blk < 7168) { in = w_qkv; out = wqkvT; N = TRIPLE;  t = blk - 4096; }
  else            { in = w_out; out = woutT; N = DMODEL;  t = blk - 7168; }
  int ntiles = N / 32;
  int n0 = (t % ntiles) * 32, k0 = (t / ntiles) * 32;
  int tx = tid & 31, ty = tid >> 5;             // 32 x 8
#pragma unroll
  for (int r = 0; r < 4; ++r)
    tile[ty + 8 * r][tx] = in[(size_t)(k0 + ty + 8 * r) * N + (n0 + tx)];
  __syncthreads();
#pragma unroll
  for (int r = 0; r < 4; ++r)
    out[(size_t)(n0 + ty + 8 * r) * K + (k0 + tx)] = f2bf(tile[tx][ty + 8 * r]);
}

// ------------------------------------------------- C[M][N] = A[M][K]bf16 * Bt[N][K]bf16^T
// m97 structure + XOR chunk swizzle: 128x128 tile, BK=64, 256 thr / 4 waves,
// global_load_lds width-16 staging into [128][64]-short LDS tiles where
// LDS slot (row, c) holds global chunk (row, c ^ (row&7))  [16B chunks, 8/row].
// Frag reads hit slot (c ^ (l16&7)) -> 2-way bank aliasing (free, m136).
template <bool BF16OUT>
__global__ __launch_bounds__(256) void gemm_bt_kernel(
    const unsigned short* __restrict__ A,
    const unsigned short* __restrict__ Bt,
    void* __restrict__ Cv,
    int M, int N, int K) {
  __shared__ short lsA[128 * 64];
  __shared__ short lsB[128 * 64];
  int tid  = threadIdx.x;
  int wave = tid >> 6, lane = tid & 63;
  int quad = lane >> 4, l16 = lane & 15;
  int wm = (wave >> 1) * 64, wn = (wave & 1) * 64;
  int m0 = blockIdx.x * 128, n0 = blockIdx.y * 128;

  f32x4 acc[4][4] = {};

  const short* Ag = (const short*)A;
  const short* Bg = (const short*)Bt;

  int row8 = lane >> 3;                       // 0..7
  int gcol = ((lane & 7) ^ row8) * 8;         // swizzled source column (shorts)
  int sw = (l16 & 7) * 8;                     // frag-read XOR (shorts)

  for (int k0 = 0; k0 < K; k0 += 64) {
    const short* Ab = Ag + (size_t)(m0 + wave * 32) * K + k0;
    const short* Bb = Bg + (size_t)(n0 + wave * 32) * K + k0;
#pragma unroll
    for (int inst = 0; inst < 4; ++inst) {
      int r = inst * 8 + row8;
      load_lds16(Ab + (size_t)r * K + gcol, &lsA[(wave * 32 + inst * 8) * 64]);
      load_lds16(Bb + (size_t)r * K + gcol, &lsB[(wave * 32 + inst * 8) * 64]);
    }
    __syncthreads();
#pragma unroll
    for (int ks = 0; ks < 2; ++ks) {
      short8 af[4], bf[4];
#pragma unroll
      for (int t = 0; t < 4; ++t) {
        int coff = ((ks * 32 + quad * 8) ^ sw);
        af[t] = *(const short8*)(&lsA[(wm + t * 16 + l16) * 64 + coff]);
        bf[t] = *(const short8*)(&lsB[(wn + t * 16 + l16) * 64 + coff]);
      }
#pragma unroll
      for (int mt = 0; mt < 4; ++mt)
#pragma unroll
        for (int nt = 0; nt < 4; ++nt)
          acc[mt][nt] = __builtin_amdgcn_mfma_f32_16x16x32_bf16(
              af[mt], bf[nt], acc[mt][nt], 0, 0, 0);
    }
    __syncthreads();
  }
#pragma unroll
  for (int mt = 0; mt < 4; ++mt)
#pragma unroll
    for (int nt = 0; nt < 4; ++nt)
#pragma unroll
      for (int r = 0; r < 4; ++r) {
        int row = m0 + wm + mt * 16 + quad * 4 + r;
        int col = n0 + wn + nt * 16 + l16;
        if (BF16OUT)
          ((unsigned short*)Cv)[(size_t)row * N + col] = f2bf(acc[mt][nt][r]);
        else
          ((float*)Cv)[(size_t)row * N + col] = acc[mt][nt][r];
      }
}

// ------------------------------------------------- MFMA flash attention v2 (bf16 in/out)
// Single-stage: the whole key union (<=192 rows) of the 64-query block is staged to LDS
// once (1 barrier), then 1..3 chunks of 64 keys run barrier-free.
// All strides are ≡4 dwords (mod 32): 2-way bank aliasing = free (m136).
#define KSTR 72    // K tile row stride (shorts):     192 x 72
#define VSTR 200   // V^T tile row stride (shorts):    64 x 200
#define PSTR 72    // P tile row stride (shorts): 4 x (16 x 72)
__global__ __launch_bounds__(256) void attn_kernel(
    const unsigned short* __restrict__ qkvb,
    unsigned short* __restrict__ attnout) {
  __shared__ short Kl[192 * KSTR];
  __shared__ short Vt[64 * VSTR];
  __shared__ short Pl[4][16 * PSTR];

  int i0 = blockIdx.x * 64, h = blockIdx.y, b = blockIdx.z;
  int tid = threadIdx.x, wave = tid >> 6, lane = tid & 63;
  int quad = lane >> 4, l16 = lane & 15;
  const unsigned short* base = qkvb + (size_t)b * SQ * TRIPLE;

  // Q A-frags (A[m=lane&15][k=quad*8+e]), held across the whole loop
  short8 qa[2];
  {
    int qi = i0 + wave * 16 + l16;
    const unsigned short* qrow = base + (size_t)qi * TRIPLE + h * DHD;
    qa[0] = *(const short8*)(qrow + quad * 8);
    qa[1] = *(const short8*)(qrow + 32 + quad * 8);
  }

  int jbase = (i0 >= WIN) ? (i0 - WIN) : 0;
  int nch = (i0 + 64 - jbase) >> 6;        // 1..3 chunks of 64 keys

  // ---- stage the whole union: K row-major, V transposed ----
  int srow_ = tid >> 3;               // 0..31
  int scol_ = (tid & 7) * 8;          // 0..56
  for (int p = 0; p < 2 * nch; ++p) {
    int r = p * 32 + srow_;
    int j = jbase + r;
    const unsigned short* kr = base + (size_t)j * TRIPLE + DMODEL + h * DHD + scol_;
    *(short8*)(&Kl[r * KSTR + scol_]) = *(const short8*)kr;
    const unsigned short* vr = base + (size_t)j * TRIPLE + 2 * DMODEL + h * DHD + scol_;
    short8 vv = *(const short8*)vr;
#pragma unroll
    for (int e = 0; e < 8; ++e)
      Vt[(scol_ + e) * VSTR + r] = vv[e];
  }
  __syncthreads();

  f32x4 o[4] = {};
  float mrow[4] = {-1e30f, -1e30f, -1e30f, -1e30f};
  float lrow[4] = {0.f, 0.f, 0.f, 0.f};
  int irow = i0 + wave * 16 + quad * 4;    // + r = query index of acc row r

  for (int c = 0; c < nch; ++c) {
    int jc = jbase + c * 64;

    // ---- S = Q K^T over 64 keys (C-layout: row=quad*4+r, col tiles nt) ----
    f32x4 s[4] = {};
#pragma unroll
    for (int ks = 0; ks < 2; ++ks)
#pragma unroll
      for (int nt = 0; nt < 4; ++nt) {
        short8 bk = *(const short8*)(&Kl[(c * 64 + nt * 16 + l16) * KSTR + ks * 32 + quad * 8]);
        s[nt] = __builtin_amdgcn_mfma_f32_16x16x32_bf16(qa[ks], bk, s[nt], 0, 0, 0);
      }
    // ---- scale + window mask ----
#pragma unroll
    for (int nt = 0; nt < 4; ++nt)
#pragma unroll
      for (int r = 0; r < 4; ++r) {
        int i_ = irow + r;
        int j_ = jc + nt * 16 + l16;
        bool ok = (j_ <= i_) && (j_ > i_ - WIN);
        s[nt][r] = ok ? s[nt][r] * 0.125f : -1e30f;
      }
    // ---- online softmax over 64 cols (4 tiles x 16 lanes) ----
    float rm[4];
#pragma unroll
    for (int r = 0; r < 4; ++r)
      rm[r] = fmaxf(fmaxf(s[0][r], s[1][r]), fmaxf(s[2][r], s[3][r]));
#pragma unroll
    for (int off = 1; off < 16; off <<= 1)
#pragma unroll
      for (int r = 0; r < 4; ++r) rm[r] = fmaxf(rm[r], __shfl_xor(rm[r], off, 64));
    float al[4];
#pragma unroll
    for (int r = 0; r < 4; ++r) {
      float mn = fmaxf(mrow[r], rm[r]);
      al[r] = __expf(mrow[r] - mn);      // exp(0)=1 when both -1e30: safe
      mrow[r] = mn;
    }
    f32x4 p[4];
#pragma unroll
    for (int nt = 0; nt < 4; ++nt)
#pragma unroll
      for (int r = 0; r < 4; ++r) p[nt][r] = __expf(s[nt][r] - mrow[r]);
    float rs[4];
#pragma unroll
    for (int r = 0; r < 4; ++r)
      rs[r] = (p[0][r] + p[1][r]) + (p[2][r] + p[3][r]);
#pragma unroll
    for (int off = 1; off < 16; off <<= 1)
#pragma unroll
      for (int r = 0; r < 4; ++r) rs[r] += __shfl_xor(rs[r], off, 64);
#pragma unroll
    for (int r = 0; r < 4; ++r) lrow[r] = lrow[r] * al[r] + rs[r];
#pragma unroll
    for (int nt = 0; nt < 4; ++nt)
#pragma unroll
      for (int r = 0; r < 4; ++r) o[nt][r] *= al[r];
    // ---- P: C-layout -> LDS -> A-frags (wave-private; DS in-order per wave) ----
#pragma unroll
    for (int nt = 0; nt < 4; ++nt)
#pragma unroll
      for (int r = 0; r < 4; ++r)
        Pl[wave][(quad * 4 + r) * PSTR + nt * 16 + l16] = f2bf(p[nt][r]);
    short8 pa[2];
    pa[0] = *(const short8*)(&Pl[wave][l16 * PSTR + quad * 8]);
    pa[1] = *(const short8*)(&Pl[wave][l16 * PSTR + 32 + quad * 8]);
    // ---- O += P V  (B-frag = Vt[d=nt*16+l16][j=ks*32+quad*8]) ----
#pragma unroll
    for (int ks = 0; ks < 2; ++ks)
#pragma unroll
      for (int nt = 0; nt < 4; ++nt) {
        short8 bv = *(const short8*)(&Vt[(nt * 16 + l16) * VSTR + c * 64 + ks * 32 + quad * 8]);
        o[nt] = __builtin_amdgcn_mfma_f32_16x16x32_bf16(pa[ks], bv, o[nt], 0, 0, 0);
      }
  }

  // ---- epilogue ----
  float inv[4];
#pragma unroll
  for (int r = 0; r < 4; ++r) inv[r] = 1.0f / lrow[r];
#pragma unroll
  for (int nt = 0; nt < 4; ++nt)
#pragma unroll
    for (int r = 0; r < 4; ++r) {
      int i_ = irow + r;
      int d_ = nt * 16 + l16;
      attnout[(size_t)(b * SQ + i_) * DMODEL + h * DHD + d_] = f2bf(o[nt][r] * inv[r]);
    }
}

// ----------------------------------------------------------------------------------
extern "C" void kernel_launch(void* const* d_in, const int* in_sizes, int n_in,
                              void* d_out, int out_size, void* d_ws, size_t ws_size,
                              hipStream_t stream) {
  const float* x     = (const float*)d_in[0];   // [2,2048,1024]
  const float* w_qkv = (const float*)d_in[1];   // [1024,3072]
  const float* w_out = (const float*)d_in[2];   // [1024,1024]
  float* out = (float*)d_out;                   // [2,2048,1024] fp32

  char* ws = (char*)d_ws;
  // workspace layout (48 MB total)
  unsigned short* xb    = (unsigned short*)(ws);               //  8 MB  [4096][1024] bf16
  unsigned short* wqkvT = (unsigned short*)(ws + 8388608);     //  6 MB  [3072][1024] bf16
  unsigned short* woutT = (unsigned short*)(ws + 14680064);    //  2 MB  [1024][1024] bf16
  unsigned short* qkvb  = (unsigned short*)(ws + 16777216);    // 24 MB  [4096][3072] bf16
  unsigned short* attn  = (unsigned short*)(ws + 41943040);    //  8 MB  [4096][1024] bf16

  // 1. fused preprocessing (cast x + transpose both weights)
  prep_kernel<<<8192, 256, 0, stream>>>(x, w_qkv, w_out, xb, wqkvT, woutT);
  // 2. qkvb = xb @ wqkvT^T   (bf16 out)
  gemm_bt_kernel<true><<<dim3((NB * SQ) / 128, TRIPLE / 128), 256, 0, stream>>>(
      xb, wqkvT, qkvb, NB * SQ, TRIPLE, DMODEL);
  // 3. MFMA flash attention (single-stage union)
  attn_kernel<<<dim3(SQ / 64, NH, NB), 256, 0, stream>>>(qkvb, attn);
  // 4. out = attn @ woutT^T  (fp32 out)
  gemm_bt_kernel<false><<<dim3((NB * SQ) / 128, DMODEL / 128), 256, 0, stream>>>(
      attn, woutT, out, NB * SQ, DMODEL, DMODEL);
}

// Round 7
// 148.067 us; speedup vs baseline: 1.2210x; 1.0373x over previous
//
#include <hip/hip_runtime.h>

// Problem constants (B,S,D)=(2,2048,1024), H=16, DH=64, WINDOW=128
#define SQ      2048
#define NB      2
#define NH      16
#define DHD     64
#define WIN     128
#define DMODEL  1024
#define TRIPLE  3072

typedef __attribute__((ext_vector_type(8))) short  short8;
typedef __attribute__((ext_vector_type(4))) float  f32x4;

__device__ __forceinline__ unsigned short f2bf(float f) {
  unsigned u = __float_as_uint(f);
  u += 0x7fff + ((u >> 16) & 1);   // RNE
  return (unsigned short)(u >> 16);
}

// direct global->LDS DMA, 16 B per lane; LDS dest = wave-uniform base + lane*16
__device__ __forceinline__ void load_lds16(const void* g, void* l) {
  __builtin_amdgcn_global_load_lds(
      (const __attribute__((address_space(1))) unsigned int*)g,
      (__attribute__((address_space(3))) unsigned int*)l, 16, 0, 0);
}

// ------------------------------------------------- fused preprocessing (1 dispatch):
// blocks [0,4096)            : cast x fp32 -> bf16 (1024 elems/block)
// blocks [4096,7168)         : transpose+cast w_qkv [1024][3072] -> [3072][1024]
// blocks [7168,8192)         : transpose+cast w_out [1024][1024] -> [1024][1024]
__global__ __launch_bounds__(256) void prep_kernel(
    const float* __restrict__ x, const float* __restrict__ w_qkv,
    const float* __restrict__ w_out,
    unsigned short* __restrict__ xb, unsigned short* __restrict__ wqkvT,
    unsigned short* __restrict__ woutT) {
  __shared__ float tile[32][33];
  int blk = blockIdx.x, tid = threadIdx.x;
  if (blk < 4096) {
    int idx = blk * 256 + tid;
    f32x4 v = ((const f32x4*)x)[idx];
    ushort4 o;
    o.x = f2bf(v[0]); o.y = f2bf(v[1]); o.z = f2bf(v[2]); o.w = f2bf(v[3]);
    ((ushort4*)xb)[idx] = o;
    return;
  }
  const float* in;
  unsigned short* out;
  int K = DMODEL, N, t;
  if (blk < 7168) { in = w_qkv; out = wqkvT; N = TRIPLE;  t = blk - 4096; }
  else            { in = w_out; out = woutT; N = DMODEL;  t = blk - 7168; }
  int ntiles = N / 32;
  int n0 = (t % ntiles) * 32, k0 = (t / ntiles) * 32;
  int tx = tid & 31, ty = tid >> 5;             // 32 x 8
#pragma unroll
  for (int r = 0; r < 4; ++r)
    tile[ty + 8 * r][tx] = in[(size_t)(k0 + ty + 8 * r) * N + (n0 + tx)];
  __syncthreads();
#pragma unroll
  for (int r = 0; r < 4; ++r)
    out[(size_t)(n0 + ty + 8 * r) * K + (k0 + tx)] = f2bf(tile[tx][ty + 8 * r]);
}

// ------------------------------------------------- C[M][N] = A[M][K]bf16 * Bt[N][K]bf16^T
// m97 structure + XOR chunk swizzle, 512 threads = 8 waves (4x2 MxN wave grid),
// each wave a 32x64 subtile (2x4 MFMA 16x16x32). Same per-wave MFMA:staging ratio
// as the 4-wave version but 2x resident waves per CU (latency hiding, m114).
// LDS slot (row, c) holds global chunk (row, c ^ (row&7)); frag reads hit
// slot (c ^ (l16&7)) -> 2-way bank aliasing (free, m136).
template <bool BF16OUT>
__global__ __launch_bounds__(512) void gemm_bt_kernel(
    const unsigned short* __restrict__ A,
    const unsigned short* __restrict__ Bt,
    void* __restrict__ Cv,
    int M, int N, int K) {
  __shared__ short lsA[128 * 64];
  __shared__ short lsB[128 * 64];
  int tid  = threadIdx.x;
  int wave = tid >> 6, lane = tid & 63;
  int quad = lane >> 4, l16 = lane & 15;
  int wm = (wave & 3) * 32;           // 4 wave-rows of 32
  int wn = (wave >> 2) * 64;          // 2 wave-cols of 64
  int m0 = blockIdx.x * 128, n0 = blockIdx.y * 128;

  f32x4 acc[2][4] = {};

  const short* Ag = (const short*)A;
  const short* Bg = (const short*)Bt;

  int row8 = lane >> 3;                       // 0..7
  int gcol = ((lane & 7) ^ row8) * 8;         // swizzled source column (shorts)
  int sw = (l16 & 7) * 8;                     // frag-read XOR (shorts)

  for (int k0 = 0; k0 < K; k0 += 64) {
    // wave stages tile rows [16w, 16w+16) of both A and B (2 insts each)
    const short* Ab = Ag + (size_t)(m0 + wave * 16) * K + k0;
    const short* Bb = Bg + (size_t)(n0 + wave * 16) * K + k0;
#pragma unroll
    for (int inst = 0; inst < 2; ++inst) {
      int r = inst * 8 + row8;
      load_lds16(Ab + (size_t)r * K + gcol, &lsA[(wave * 16 + inst * 8) * 64]);
      load_lds16(Bb + (size_t)r * K + gcol, &lsB[(wave * 16 + inst * 8) * 64]);
    }
    __syncthreads();
#pragma unroll
    for (int ks = 0; ks < 2; ++ks) {
      int coff = ((ks * 32 + quad * 8) ^ sw);
      short8 af[2], bf[4];
#pragma unroll
      for (int t = 0; t < 2; ++t)
        af[t] = *(const short8*)(&lsA[(wm + t * 16 + l16) * 64 + coff]);
#pragma unroll
      for (int t = 0; t < 4; ++t)
        bf[t] = *(const short8*)(&lsB[(wn + t * 16 + l16) * 64 + coff]);
#pragma unroll
      for (int mt = 0; mt < 2; ++mt)
#pragma unroll
        for (int nt = 0; nt < 4; ++nt)
          acc[mt][nt] = __builtin_amdgcn_mfma_f32_16x16x32_bf16(
              af[mt], bf[nt], acc[mt][nt], 0, 0, 0);
    }
    __syncthreads();
  }
#pragma unroll
  for (int mt = 0; mt < 2; ++mt)
#pragma unroll
    for (int nt = 0; nt < 4; ++nt)
#pragma unroll
      for (int r = 0; r < 4; ++r) {
        int row = m0 + wm + mt * 16 + quad * 4 + r;
        int col = n0 + wn + nt * 16 + l16;
        if (BF16OUT)
          ((unsigned short*)Cv)[(size_t)row * N + col] = f2bf(acc[mt][nt][r]);
        else
          ((float*)Cv)[(size_t)row * N + col] = acc[mt][nt][r];
      }
}

// ------------------------------------------------- MFMA flash attention v2 (bf16 in/out)
// Single-stage: the whole key union (<=192 rows) of the 64-query block is staged to LDS
// once (1 barrier), then 1..3 chunks of 64 keys run barrier-free.
// All strides are ≡4 dwords (mod 32): 2-way bank aliasing = free (m136).
#define KSTR 72    // K tile row stride (shorts):     192 x 72
#define VSTR 200   // V^T tile row stride (shorts):    64 x 200
#define PSTR 72    // P tile row stride (shorts): 4 x (16 x 72)
__global__ __launch_bounds__(256) void attn_kernel(
    const unsigned short* __restrict__ qkvb,
    unsigned short* __restrict__ attnout) {
  __shared__ short Kl[192 * KSTR];
  __shared__ short Vt[64 * VSTR];
  __shared__ short Pl[4][16 * PSTR];

  int i0 = blockIdx.x * 64, h = blockIdx.y, b = blockIdx.z;
  int tid = threadIdx.x, wave = tid >> 6, lane = tid & 63;
  int quad = lane >> 4, l16 = lane & 15;
  const unsigned short* base = qkvb + (size_t)b * SQ * TRIPLE;

  // Q A-frags (A[m=lane&15][k=quad*8+e]), held across the whole loop
  short8 qa[2];
  {
    int qi = i0 + wave * 16 + l16;
    const unsigned short* qrow = base + (size_t)qi * TRIPLE + h * DHD;
    qa[0] = *(const short8*)(qrow + quad * 8);
    qa[1] = *(const short8*)(qrow + 32 + quad * 8);
  }

  int jbase = (i0 >= WIN) ? (i0 - WIN) : 0;
  int nch = (i0 + 64 - jbase) >> 6;        // 1..3 chunks of 64 keys

  // ---- stage the whole union: K row-major, V transposed ----
  int srow_ = tid >> 3;               // 0..31
  int scol_ = (tid & 7) * 8;          // 0..56
  for (int p = 0; p < 2 * nch; ++p) {
    int r = p * 32 + srow_;
    int j = jbase + r;
    const unsigned short* kr = base + (size_t)j * TRIPLE + DMODEL + h * DHD + scol_;
    *(short8*)(&Kl[r * KSTR + scol_]) = *(const short8*)kr;
    const unsigned short* vr = base + (size_t)j * TRIPLE + 2 * DMODEL + h * DHD + scol_;
    short8 vv = *(const short8*)vr;
#pragma unroll
    for (int e = 0; e < 8; ++e)
      Vt[(scol_ + e) * VSTR + r] = vv[e];
  }
  __syncthreads();

  f32x4 o[4] = {};
  float mrow[4] = {-1e30f, -1e30f, -1e30f, -1e30f};
  float lrow[4] = {0.f, 0.f, 0.f, 0.f};
  int irow = i0 + wave * 16 + quad * 4;    // + r = query index of acc row r

  for (int c = 0; c < nch; ++c) {
    int jc = jbase + c * 64;

    // ---- S = Q K^T over 64 keys (C-layout: row=quad*4+r, col tiles nt) ----
    f32x4 s[4] = {};
#pragma unroll
    for (int ks = 0; ks < 2; ++ks)
#pragma unroll
      for (int nt = 0; nt < 4; ++nt) {
        short8 bk = *(const short8*)(&Kl[(c * 64 + nt * 16 + l16) * KSTR + ks * 32 + quad * 8]);
        s[nt] = __builtin_amdgcn_mfma_f32_16x16x32_bf16(qa[ks], bk, s[nt], 0, 0, 0);
      }
    // ---- scale + window mask ----
#pragma unroll
    for (int nt = 0; nt < 4; ++nt)
#pragma unroll
      for (int r = 0; r < 4; ++r) {
        int i_ = irow + r;
        int j_ = jc + nt * 16 + l16;
        bool ok = (j_ <= i_) && (j_ > i_ - WIN);
        s[nt][r] = ok ? s[nt][r] * 0.125f : -1e30f;
      }
    // ---- online softmax over 64 cols (4 tiles x 16 lanes) ----
    float rm[4];
#pragma unroll
    for (int r = 0; r < 4; ++r)
      rm[r] = fmaxf(fmaxf(s[0][r], s[1][r]), fmaxf(s[2][r], s[3][r]));
#pragma unroll
    for (int off = 1; off < 16; off <<= 1)
#pragma unroll
      for (int r = 0; r < 4; ++r) rm[r] = fmaxf(rm[r], __shfl_xor(rm[r], off, 64));
    float al[4];
#pragma unroll
    for (int r = 0; r < 4; ++r) {
      float mn = fmaxf(mrow[r], rm[r]);
      al[r] = __expf(mrow[r] - mn);      // exp(0)=1 when both -1e30: safe
      mrow[r] = mn;
    }
    f32x4 p[4];
#pragma unroll
    for (int nt = 0; nt < 4; ++nt)
#pragma unroll
      for (int r = 0; r < 4; ++r) p[nt][r] = __expf(s[nt][r] - mrow[r]);
    float rs[4];
#pragma unroll
    for (int r = 0; r < 4; ++r)
      rs[r] = (p[0][r] + p[1][r]) + (p[2][r] + p[3][r]);
#pragma unroll
    for (int off = 1; off < 16; off <<= 1)
#pragma unroll
      for (int r = 0; r < 4; ++r) rs[r] += __shfl_xor(rs[r], off, 64);
#pragma unroll
    for (int r = 0; r < 4; ++r) lrow[r] = lrow[r] * al[r] + rs[r];
#pragma unroll
    for (int nt = 0; nt < 4; ++nt)
#pragma unroll
      for (int r = 0; r < 4; ++r) o[nt][r] *= al[r];
    // ---- P: C-layout -> LDS -> A-frags (wave-private; DS in-order per wave) ----
#pragma unroll
    for (int nt = 0; nt < 4; ++nt)
#pragma unroll
      for (int r = 0; r < 4; ++r)
        Pl[wave][(quad * 4 + r) * PSTR + nt * 16 + l16] = f2bf(p[nt][r]);
    short8 pa[2];
    pa[0] = *(const short8*)(&Pl[wave][l16 * PSTR + quad * 8]);
    pa[1] = *(const short8*)(&Pl[wave][l16 * PSTR + 32 + quad * 8]);
    // ---- O += P V  (B-frag = Vt[d=nt*16+l16][j=ks*32+quad*8]) ----
#pragma unroll
    for (int ks = 0; ks < 2; ++ks)
#pragma unroll
      for (int nt = 0; nt < 4; ++nt) {
        short8 bv = *(const short8*)(&Vt[(nt * 16 + l16) * VSTR + c * 64 + ks * 32 + quad * 8]);
        o[nt] = __builtin_amdgcn_mfma_f32_16x16x32_bf16(pa[ks], bv, o[nt], 0, 0, 0);
      }
  }

  // ---- epilogue ----
  float inv[4];
#pragma unroll
  for (int r = 0; r < 4; ++r) inv[r] = 1.0f / lrow[r];
#pragma unroll
  for (int nt = 0; nt < 4; ++nt)
#pragma unroll
    for (int r = 0; r < 4; ++r) {
      int i_ = irow + r;
      int d_ = nt * 16 + l16;
      attnout[(size_t)(b * SQ + i_) * DMODEL + h * DHD + d_] = f2bf(o[nt][r] * inv[r]);
    }
}

// ----------------------------------------------------------------------------------
extern "C" void kernel_launch(void* const* d_in, const int* in_sizes, int n_in,
                              void* d_out, int out_size, void* d_ws, size_t ws_size,
                              hipStream_t stream) {
  const float* x     = (const float*)d_in[0];   // [2,2048,1024]
  const float* w_qkv = (const float*)d_in[1];   // [1024,3072]
  const float* w_out = (const float*)d_in[2];   // [1024,1024]
  float* out = (float*)d_out;                   // [2,2048,1024] fp32

  char* ws = (char*)d_ws;
  // workspace layout (48 MB total)
  unsigned short* xb    = (unsigned short*)(ws);               //  8 MB  [4096][1024] bf16
  unsigned short* wqkvT = (unsigned short*)(ws + 8388608);     //  6 MB  [3072][1024] bf16
  unsigned short* woutT = (unsigned short*)(ws + 14680064);    //  2 MB  [1024][1024] bf16
  unsigned short* qkvb  = (unsigned short*)(ws + 16777216);    // 24 MB  [4096][3072] bf16
  unsigned short* attn  = (unsigned short*)(ws + 41943040);    //  8 MB  [4096][1024] bf16

  // 1. fused preprocessing (cast x + transpose both weights)
  prep_kernel<<<8192, 256, 0, stream>>>(x, w_qkv, w_out, xb, wqkvT, woutT);
  // 2. qkvb = xb @ wqkvT^T   (bf16 out)
  gemm_bt_kernel<true><<<dim3((NB * SQ) / 128, TRIPLE / 128), 512, 0, stream>>>(
      xb, wqkvT, qkvb, NB * SQ, TRIPLE, DMODEL);
  // 3. MFMA flash attention (single-stage union)
  attn_kernel<<<dim3(SQ / 64, NH, NB), 256, 0, stream>>>(qkvb, attn);
  // 4. out = attn @ woutT^T  (fp32 out)
  gemm_bt_kernel<false><<<dim3((NB * SQ) / 128, DMODEL / 128), 512, 0, stream>>>(
      attn, woutT, out, NB * SQ, DMODEL, DMODEL);
}